// Round 2
// baseline (524.020 us; speedup 1.0000x reference)
//
#include <hip/hip_runtime.h>

#define K_TAGS 50
#define T_MAX 256
#define START_TAG 48
#define END_TAG 49
#define LOG2E 1.4426950408889634f
#define LN2 0.6931471805599453f
#define KK 2500   // dwords per 50x50 step matrix

// hardware transcendentals: v_exp_f32 is 2^x, v_log_f32 is log2(x)
#define EXP2F(x) __builtin_amdgcn_exp2f(x)
#define LOG2F(x) __builtin_amdgcn_logf(x)

__device__ __forceinline__ float rdlane(float v, int i) {
    return __int_as_float(__builtin_amdgcn_readlane(__float_as_int(v), i));
}

// PRODUCER/CONSUMER WAVE SPECIALIZATION, one direction per block.
//   grid = 2*B blocks of 256 threads: block (2b+0) runs the FORWARD half of
//   batch b, block (2b+1) the BACKWARD half. 256 blocks == 256 CUs, so every
//   wave gets its own SIMD (no issue-slot sharing with the serial chain).
// Within a block:
//   wave 0  = consumer: runs ONLY the true recurrence. Per step: 25 ds_read_b64
//             of the exp'd matrix column/row + 50 readlane*FMA + exponent rescale.
//   waves 1-3 = producers: rows {0-16,17-33,34-49}. Load scores (4-deep register
//             pipeline), exp off the critical path, stage into double-buffered LDS
//             (fwd: column-contiguous [j*50+i]; bwd: row-contiguous [i*50+j]).
// One s_barrier per step (double buffer => write parity != read parity).
// Split: fwd covers t=1..m, bwd folds t=len-1 then t=len-2..m+1, m=(len-2)/2.
// Results u (fwd) and v (bwd) go to workspace; combine kernel does Z = u.v.
__global__ __launch_bounds__(256, 1) void crf_fwd_kernel(
    const float* __restrict__ scores, const int* __restrict__ targets,
    const int* __restrict__ lengths, float* __restrict__ accum,
    float* __restrict__ uv)
{
    const int b    = blockIdx.x >> 1;
    const int dir  = blockIdx.x & 1;      // 0 = forward, 1 = backward
    const int tid  = threadIdx.x;
    const int wave = tid >> 6;
    const int lane = tid & 63;
    const int len  = lengths[b];
    const float* __restrict__ sp = scores + (size_t)b * T_MAX * KK;

    __shared__ float buf[2 * KK];         // double-buffered exp'd step matrix (20 KB)

    const int m = (len - 2) / 2;          // fwd steps t=1..m
    int count = dir ? (len - 2 - m) : m;  // recurrence steps this block runs
    if (count < 0) count = 0;
    const int nmac = (count + 3) >> 2;

    // ---- gold score: fwd block only, one timestep per thread (256 thr) ----
    if (dir == 0) {
        float g = 0.f;
        if (tid < len) g = sp[(size_t)tid * KK + targets[b * T_MAX + tid]];
        #pragma unroll
        for (int off = 32; off; off >>= 1) g += __shfl_down(g, off, 64);
        if (lane == 0) atomicAdd(&accum[1], g);
    }

    if (wave == 0) {
        // =========================== consumer ===========================
        const int j = (lane < K_TAGS) ? lane : (K_TAGS - 1);
        float L, M;
        if (dir == 0) {
            float bcur = sp[START_TAG * K_TAGS + j] * LOG2E;   // t=0, row START
            M = rdlane(bcur, 0);
            L = EXP2F(bcur - M);
        } else {
            M = 0.f;
            if (len >= 2)   // fold t=len-1: v = exp(s[:,END])
                L = EXP2F(sp[(size_t)(len - 1) * KK + j * K_TAGS + END_TAG] * LOG2E);
            else
                L = (j == END_TAG) ? 1.f : 0.f;
        }
        __syncthreads();                  // prologue: buf parity 0 ready

        for (int mi = 0; mi < nmac; ++mi) {
            const int s0 = mi << 2;
            #pragma unroll
            for (int k = 0; k < 4; ++k) {
                if (s0 + k < count) {
                    const float2* br =
                        (const float2*)(buf + (k & 1) * KK + j * K_TAGS);
                    float R[50];
                    #pragma unroll
                    for (int q = 0; q < 25; ++q)
                        *(float2*)&R[2 * q] = br[q];
                    float l0 = rdlane(L, 0);
                    int   ei = (__float_as_int(l0) >> 23) & 0xFF;
                    float scale = __int_as_float((254 - ei) << 23);
                    float a0 = 0.f, a1 = 0.f, a2 = 0.f, a3 = 0.f, a4 = 0.f;
                    #pragma unroll
                    for (int i = 0; i < 50; i += 5) {
                        a0 = __builtin_fmaf(R[i + 0], rdlane(L, i + 0), a0);
                        a1 = __builtin_fmaf(R[i + 1], rdlane(L, i + 1), a1);
                        a2 = __builtin_fmaf(R[i + 2], rdlane(L, i + 2), a2);
                        a3 = __builtin_fmaf(R[i + 3], rdlane(L, i + 3), a3);
                        a4 = __builtin_fmaf(R[i + 4], rdlane(L, i + 4), a4);
                    }
                    L = (((a0 + a1) + (a2 + a3)) + a4) * scale;
                    M += (float)(ei - 127);
                }
                __syncthreads();
            }
        }
        // publish result vector for the combine kernel
        float* w = uv + (size_t)(dir ? (gridDim.x >> 1) + b : b) * 64;
        if (lane < K_TAGS) w[lane] = L;
        if (lane == 0)     w[K_TAGS] = M;
    } else {
        // =========================== producers ==========================
        const int  r0  = 17 * (wave - 1);               // row range [r0, r0+17)
        const bool act = lane < K_TAGS;
        const int  j   = act ? lane : (K_TAGS - 1);
        float S[4][17];                                  // 4-deep load pipeline

        // matrix index for recurrence step s
        auto tof = [&](int s) { return dir ? (len - 2 - s) : (s + 1); };

        // prologue: issue loads for steps 0..2; exp+write step 0 -> parity 0
        #pragma unroll
        for (int q = 0; q < 3; ++q) {
            if (q < count && act) {
                const float* p = sp + (size_t)tof(q) * KK + j;
                #pragma unroll
                for (int r = 0; r < 17; ++r)
                    if (r0 + r < K_TAGS) S[q][r] = p[(r0 + r) * K_TAGS];
            }
        }
        __builtin_amdgcn_sched_barrier(0);
        if (0 < count && act) {
            #pragma unroll
            for (int r = 0; r < 17; ++r)
                if (r0 + r < K_TAGS) {
                    int   row = r0 + r;
                    float e = EXP2F(S[0][r] * LOG2E);
                    buf[dir ? (row * K_TAGS + j) : (j * K_TAGS + row)] = e;
                }
        }
        __syncthreads();

        for (int mi = 0; mi < nmac; ++mi) {
            const int s0 = mi << 2;
            #pragma unroll
            for (int k = 0; k < 4; ++k) {
                // issue loads for step s0+k+3 into set (k+3)&3  (2-step latency gap)
                if (s0 + k + 3 < count && act) {
                    const float* p = sp + (size_t)tof(s0 + k + 3) * KK + j;
                    #pragma unroll
                    for (int r = 0; r < 17; ++r)
                        if (r0 + r < K_TAGS) S[(k + 3) & 3][r] = p[(r0 + r) * K_TAGS];
                }
                __builtin_amdgcn_sched_barrier(0);
                // exp + stage step s0+k+1 into parity (k+1)&1
                if (s0 + k + 1 < count && act) {
                    float* bw = buf + ((k + 1) & 1) * KK;
                    #pragma unroll
                    for (int r = 0; r < 17; ++r)
                        if (r0 + r < K_TAGS) {
                            int   row = r0 + r;
                            float e = EXP2F(S[(k + 1) & 3][r] * LOG2E);
                            bw[dir ? (row * K_TAGS + j) : (j * K_TAGS + row)] = e;
                        }
                }
                __syncthreads();
            }
        }
    }
}

// per-batch combine: Z_b = Mu + Mv + log2(sum_j u[j]*v[j])
__global__ void combine_kernel(const float* __restrict__ uv,
                               float* __restrict__ accum, int B)
{
    const int b = blockIdx.x, lane = threadIdx.x;
    const float* U = uv + (size_t)b * 64;
    const float* V = uv + (size_t)(B + b) * 64;
    float prod = (lane < K_TAGS) ? U[lane] * V[lane] : 0.f;
    #pragma unroll
    for (int off = 32; off; off >>= 1) prod += __shfl_down(prod, off, 64);
    if (lane == 0) {
        float z = (U[K_TAGS] + V[K_TAGS] + LOG2F(prod)) * LN2;
        atomicAdd(&accum[0], z);
    }
}

__global__ void finalize_kernel(const float* __restrict__ accum,
                                float* __restrict__ out, float invB)
{
    out[0] = (accum[0] - accum[1]) * invB;
}

extern "C" void kernel_launch(void* const* d_in, const int* in_sizes, int n_in,
                              void* d_out, int out_size, void* d_ws, size_t ws_size,
                              hipStream_t stream)
{
    const float* scores  = (const float*)d_in[0];
    const int*   targets = (const int*)d_in[1];
    const int*   lengths = (const int*)d_in[2];
    const int B = in_sizes[2];

    float* accum = (float*)d_ws;
    float* uv    = (float*)d_ws + 16;     // u[B][64] then v[B][64]
    hipMemsetAsync(accum, 0, 2 * sizeof(float), stream);
    crf_fwd_kernel<<<2 * B, 256, 0, stream>>>(scores, targets, lengths, accum, uv);
    combine_kernel<<<B, 64, 0, stream>>>(uv, accum, B);
    finalize_kernel<<<1, 1, 0, stream>>>(accum, (float*)d_out, 1.0f / (float)B);
}